// Round 17
// baseline (91.955 us; speedup 1.0000x reference)
//
#include <hip/hip_runtime.h>
#include <hip/hip_bf16.h>
#include <cstdint>
#include <cstddef>

#define NG 32
#define NP 64
#define ND 512
#define HW 192
#define KS 32  // number of K=16 slices in pre-tiled layout
#define EPSV 1e-5f

typedef _Float16 half8 __attribute__((ext_vector_type(8)));
typedef float floatx4 __attribute__((ext_vector_type(4)));
typedef float floatx16 __attribute__((ext_vector_type(16)));

// ---- unified pre-pass: src[b][d][x] f32 -> T[b][ks][rb][hi][l31][j] fp16
// (d = ks*16 + hi*8 + j, x = rb*32 + l31).  Fragment-ready AND stage-ready.
__global__ __launch_bounds__(256) void prep_frag(const float* __restrict__ gal,
                                                 const float* __restrict__ prob,
                                                 _Float16* __restrict__ galT4,
                                                 _Float16* __restrict__ probT4) {
  __shared__ float lds[16 * 192];
  const int z = blockIdx.x;   // 0..95: first NP probes, then NG gals
  const int ks = blockIdx.y;  // 0..31
  const float* src;
  _Float16* dst;
  if (z < NP) {
    src = prob + (size_t)z * ND * HW;
    dst = probT4 + (size_t)z * 98304;
  } else {
    src = gal + (size_t)(z - NP) * ND * HW;
    dst = galT4 + (size_t)(z - NP) * 98304;
  }
  src += (size_t)ks * 16 * HW;
  dst += (size_t)ks * 3072;
  const int t = threadIdx.x;
#pragma unroll
  for (int i = 0; i < 12; ++i) lds[i * 256 + t] = src[i * 256 + t];
  __syncthreads();
#pragma unroll
  for (int r = 0; r < 2; ++r) {
    const int h = r * 256 + t;  // h = rb*64 + hi*32 + l31, 384 slots
    if (h < 384) {
      const int rb = h >> 6, hi = (h >> 5) & 1, l31 = h & 31;
      half8 v;
#pragma unroll
      for (int j = 0; j < 8; ++j) v[j] = (_Float16)lds[(hi * 8 + j) * 192 + rb * 32 + l31];
      *(half8*)(dst + (size_t)h * 8) = v;
    }
  }
}

// ---- async 16B global -> LDS
__device__ __forceinline__ void g2l16(const void* g, void* l) {
  __builtin_amdgcn_global_load_lds(
      (const __attribute__((address_space(1))) void*)g,
      (__attribute__((address_space(3))) void*)l, 16, 0, 0);
}

// ---- main fused kernel: one WG (256 thr, 4 waves) per (g,p) pair ----
// R16 frame (BK=32, triple buffer, counted vmcnt, raw barriers) with the
// m196 lever: per-phase FINE INTERLEAVE.  Fragment registers are double-
// buffered (set0/set1) and each phase overlaps {MFMA9 on current set} with
// {READ6 prefetch of the next phase's set} and {STAGE of kt+2} in ONE
// scheduling region -- no sched_barrier walls, so hipcc interleaves ds_read
// with MFMA (its auto-lgkmcnt handles the dependences).  2 barriers per kt.
// vmcnt(6) at phase-1 entry == stage(kt+1) landed, stage(kt+2) in flight.
__global__ __launch_bounds__(256, 2) void qaconv_main(
    const _Float16* __restrict__ galT4, const _Float16* __restrict__ probT4,
    const float* __restrict__ bn_w, const float* __restrict__ bn_b,
    const float* __restrict__ bn_m, const float* __restrict__ bn_v,
    const float* __restrict__ fc_w, const float* __restrict__ fc_b,
    const float* __restrict__ lbn_w, const float* __restrict__ lbn_b,
    const float* __restrict__ lbn_m, const float* __restrict__ lbn_v,
    float* __restrict__ out) {
  // K-loop: 3 buffers x [A 12KB | B 12KB] = 73728 B; epilogue overlays
  // rowbuf[192][66] f32 (50688 B) on the same storage.
  __shared__ __align__(16) char shmem[73728];
  __shared__ float colp[2][HW];
  __shared__ float wsum[4];
  float(*rowbuf)[66] = (float(*)[66])shmem;

  const int bid = blockIdx.x;
  const int g = bid >> 6, p = bid & 63;

  const int t = threadIdx.x;
  const int lane = t & 63, wid = t >> 6;
  const int wr = wid & 1;   // probe-row half (y block of 96)
  const int wc = wid >> 1;  // gal-col half (x block of 96)
  const int l31 = lane & 31, hi = lane >> 5;

  // staging sources (per-lane): one BK=32 tile = 12KB linear per operand.
  const _Float16* pAl = probT4 + (size_t)p * 98304 + wid * 512 + lane * 8;
  const _Float16* pBl = galT4 + (size_t)g * 98304 + wid * 512 + lane * 8;
  const int sdst = wid * 1024;  // wave-uniform LDS dest base (+ lane*16 by HW)

  char* const b0 = shmem;
  char* const b1 = shmem + 24576;
  char* const b2 = shmem + 49152;

  floatx16 acc[3][3];
#pragma unroll
  for (int ii = 0; ii < 3; ++ii)
#pragma unroll
    for (int jj = 0; jj < 3; ++jj) acc[ii][jj] = (floatx16)0.f;

  half8 raf0[3], rbf0[3], raf1[3], rbf1[3];

#define STAGE(kt_, base_)                                            \
  {                                                                  \
    char* db_ = (base_) + sdst;                                      \
    const _Float16* sa_ = pAl + (size_t)(kt_)*6144;                  \
    const _Float16* sb_ = pBl + (size_t)(kt_)*6144;                  \
    g2l16(sa_, db_);                                                 \
    g2l16(sa_ + 2048, db_ + 4096);                                   \
    g2l16(sa_ + 4096, db_ + 8192);                                   \
    g2l16(sb_, db_ + 12288);                                         \
    g2l16(sb_ + 2048, db_ + 16384);                                  \
    g2l16(sb_ + 4096, db_ + 20480);                                  \
  }

#define READ6(AF, BF, base_, kc_)                                    \
  {                                                                  \
    const char* bA_ = (base_) + (kc_)*6144;                          \
    const char* bB_ = (base_) + 12288 + (kc_)*6144;                  \
    AF[0] = *(const half8*)(bA_ + (wr * 3 + 0) * 1024 + lane * 16);  \
    AF[1] = *(const half8*)(bA_ + (wr * 3 + 1) * 1024 + lane * 16);  \
    AF[2] = *(const half8*)(bA_ + (wr * 3 + 2) * 1024 + lane * 16);  \
    BF[0] = *(const half8*)(bB_ + (wc * 3 + 0) * 1024 + lane * 16);  \
    BF[1] = *(const half8*)(bB_ + (wc * 3 + 1) * 1024 + lane * 16);  \
    BF[2] = *(const half8*)(bB_ + (wc * 3 + 2) * 1024 + lane * 16);  \
  }

#define MFMA9(AF, BF)                                                            \
  {                                                                              \
    __builtin_amdgcn_s_setprio(1);                                               \
    _Pragma("unroll") for (int ii = 0; ii < 3; ++ii)                             \
        _Pragma("unroll") for (int jj = 0; jj < 3; ++jj)                         \
            acc[ii][jj] = __builtin_amdgcn_mfma_f32_32x32x16_f16(AF[ii], BF[jj], \
                                                                 acc[ii][jj], 0, 0, 0); \
    __builtin_amdgcn_s_setprio(0);                                               \
  }

  // SLOT = one kt = two phases.  rdb_: buffer of kt; nrdb_: buffer of kt+1.
#define SLOT(kt_, rdb_, nrdb_, stb_, doStage_, vmW_)                 \
  {                                                                  \
    /* P0: MFMA(set0=kt,kc0) || read kc1->set1 || stage(kt+2) */     \
    if (doStage_) STAGE((kt_) + 2, stb_)                             \
    READ6(raf1, rbf1, rdb_, 1)                                       \
    MFMA9(raf0, rbf0)                                                \
    __builtin_amdgcn_s_barrier();                                    \
    /* P1: MFMA(set1=kt,kc1) || read (kt+1,kc0)->set0 */             \
    asm volatile("s_waitcnt vmcnt(" #vmW_ ")" ::: "memory");         \
    READ6(raf0, rbf0, nrdb_, 0)                                      \
    MFMA9(raf1, rbf1)                                                \
    __builtin_amdgcn_s_barrier();                                    \
  }

  // prologue: stage tiles 0,1; wait stage(0); first fragment read
  STAGE(0, b0)
  STAGE(1, b1)
  asm volatile("s_waitcnt vmcnt(6)" ::: "memory");
  __builtin_amdgcn_s_barrier();
  READ6(raf0, rbf0, b0, 0)

#pragma unroll 1
  for (int m = 0; m < 4; ++m) {  // kt = 0..11
    SLOT(3 * m + 0, b0, b1, b2, true, 6)
    SLOT(3 * m + 1, b1, b2, b0, true, 6)
    SLOT(3 * m + 2, b2, b0, b1, true, 6)
  }
  SLOT(12, b0, b1, b2, true, 6)   // stage(14)->b2
  SLOT(13, b1, b2, b0, true, 6)   // stage(15)->b0
  SLOT(14, b2, b0, b1, false, 0)  // vmcnt(0): stage(15) fully landed
  // kt = 15 (buffer b0), no next prefetch:
  READ6(raf1, rbf1, b0, 1)
  MFMA9(raf0, rbf0)
  MFMA9(raf1, rbf1)
#undef STAGE
#undef READ6
#undef MFMA9
#undef SLOT

  // ---- epilogue: dual-axis max ----
  // C/D map: col X = wc*96 + fb*32 + l31, row Y = wr*96 + fa*32 + (e&3)+8*(e>>2)+4*hi
#pragma unroll
  for (int fb = 0; fb < 3; ++fb) {
    float v = -3.4e38f;
#pragma unroll
    for (int fa = 0; fa < 3; ++fa)
#pragma unroll
      for (int e = 0; e < 16; ++e) v = fmaxf(v, acc[fa][fb][e]);
    v = fmaxf(v, __shfl_xor(v, 32));
    if (lane < 32) colp[wr][wc * 96 + fb * 32 + lane] = v;
  }
  __syncthreads();  // all waves done with LDS tiles -> safe to overlay rowbuf
  // rowmax partials -> rowbuf (overlays tile storage)
#pragma unroll
  for (int fa = 0; fa < 3; ++fa)
#pragma unroll
    for (int e = 0; e < 16; ++e) {
      float rv = acc[fa][0][e];
      rv = fmaxf(rv, acc[fa][1][e]);
      rv = fmaxf(rv, acc[fa][2][e]);
      const int Y = wr * 96 + fa * 32 + (e & 3) + 8 * (e >> 2) + 4 * hi;
      rowbuf[Y][wc * 32 + l31] = rv;
    }
  __syncthreads();

  // ---- fused BN -> fc dot -> logit BN -> sigmoid ----
  float partial = 0.f;
  if (t < HW) {
    const float* rb = rowbuf[t];
    float rmax = -3.4e38f;
#pragma unroll
    for (int j = 0; j < 16; ++j) {
      const floatx4 v = *(const floatx4*)&rb[j * 4];
      rmax = fmaxf(rmax, fmaxf(fmaxf(v[0], v[1]), fmaxf(v[2], v[3])));
    }
    const float cmax = fmaxf(colp[0][t], colp[1][t]);
    const float scale = bn_w[0] / sqrtf(bn_v[0] + EPSV);
    const float bm = bn_m[0], bb = bn_b[0];
    partial = ((cmax - bm) * scale + bb) * fc_w[t] +
              ((rmax - bm) * scale + bb) * fc_w[HW + t];
  }
#pragma unroll
  for (int off = 1; off < 64; off <<= 1) partial += __shfl_xor(partial, off);
  if (lane == 0) wsum[wid] = partial;
  __syncthreads();
  if (t == 0) {
    const float sum = fc_b[0] + wsum[0] + wsum[1] + wsum[2] + wsum[3];
    const float logit = (sum - lbn_m[0]) * (lbn_w[0] / sqrtf(lbn_v[0] + EPSV)) + lbn_b[0];
    out[bid] = 1.f / (1.f + expf(-logit * 0.1f));
  }
}

// ---------------- naive f32 fallback (only if ws too small) ----------------
__global__ __launch_bounds__(256) void qaconv_naive(
    const float* __restrict__ gal, const float* __restrict__ prob,
    const float* __restrict__ bn_w, const float* __restrict__ bn_b,
    const float* __restrict__ bn_m, const float* __restrict__ bn_v,
    const float* __restrict__ fc_w, const float* __restrict__ fc_b,
    const float* __restrict__ lbn_w, const float* __restrict__ lbn_b,
    const float* __restrict__ lbn_m, const float* __restrict__ lbn_v,
    float* __restrict__ out) {
  __shared__ float prow[ND];
  __shared__ float rowmaxs[HW];
  __shared__ float colmaxs[HW];
  __shared__ float red[4];
  const int bid = blockIdx.x;
  const int g = bid >> 6, p = bid & 63;
  const int t = threadIdx.x, lane = t & 63, wid = t >> 6;
  const float* gp = gal + (size_t)g * ND * HW;
  const float* pp = prob + (size_t)p * ND * HW;
  float colmax = -3.4e38f;
  for (int y = 0; y < HW; ++y) {
    for (int k = t; k < ND; k += 256) prow[k] = pp[(size_t)k * HW + y];
    __syncthreads();
    float sv = -3.4e38f;
    if (t < HW) {
      sv = 0.f;
      for (int k = 0; k < ND; ++k) sv = fmaf(prow[k], gp[(size_t)k * HW + t], sv);
      colmax = fmaxf(colmax, sv);
    }
    float m = sv;
#pragma unroll
    for (int off = 1; off < 64; off <<= 1) m = fmaxf(m, __shfl_xor(m, off));
    if (lane == 0) red[wid] = m;
    __syncthreads();
    if (t == 0) rowmaxs[y] = fmaxf(fmaxf(red[0], red[1]), fmaxf(red[2], red[3]));
    __syncthreads();
  }
  if (t < HW) colmaxs[t] = colmax;
  __syncthreads();
  float partial = 0.f;
  for (int j = t; j < 2 * HW; j += 256) {
    const float v = (j < HW) ? colmaxs[j] : rowmaxs[j - HW];
    const float sc = (v - bn_m[0]) * (bn_w[0] / sqrtf(bn_v[0] + EPSV)) + bn_b[0];
    partial += sc * fc_w[j];
  }
#pragma unroll
  for (int off = 1; off < 64; off <<= 1) partial += __shfl_xor(partial, off);
  if (lane == 0) red[wid] = partial;
  __syncthreads();
  if (t == 0) {
    const float sum = fc_b[0] + red[0] + red[1] + red[2] + red[3];
    const float logit = (sum - lbn_m[0]) * (lbn_w[0] / sqrtf(lbn_v[0] + EPSV)) + lbn_b[0];
    out[bid] = 1.f / (1.f + expf(-logit * 0.1f));
  }
}

extern "C" void kernel_launch(void* const* d_in, const int* in_sizes, int n_in,
                              void* d_out, int out_size, void* d_ws, size_t ws_size,
                              hipStream_t stream) {
  const float* gal = (const float*)d_in[0];
  const float* prob = (const float*)d_in[1];
  const float* bn_w = (const float*)d_in[2];
  const float* bn_b = (const float*)d_in[3];
  const float* bn_m = (const float*)d_in[4];
  const float* bn_v = (const float*)d_in[5];
  const float* fc_w = (const float*)d_in[6];
  const float* fc_b = (const float*)d_in[7];
  const float* lbn_w = (const float*)d_in[8];
  const float* lbn_b = (const float*)d_in[9];
  const float* lbn_m = (const float*)d_in[10];
  const float* lbn_v = (const float*)d_in[11];
  float* out = (float*)d_out;

  const size_t probT4_elems = (size_t)NP * 98304;  // 6.29M halves
  const size_t galT4_elems = (size_t)NG * 98304;   // 3.15M halves
  const size_t ws_needed = (probT4_elems + galT4_elems) * sizeof(_Float16);
  if (ws_size >= ws_needed) {
    _Float16* probT4 = (_Float16*)d_ws;
    _Float16* galT4 = probT4 + probT4_elems;
    prep_frag<<<dim3(NP + NG, KS), dim3(256), 0, stream>>>(gal, prob, galT4, probT4);
    qaconv_main<<<dim3(NG * NP), dim3(256), 0, stream>>>(
        galT4, probT4, bn_w, bn_b, bn_m, bn_v, fc_w, fc_b, lbn_w, lbn_b, lbn_m, lbn_v, out);
  } else {
    qaconv_naive<<<dim3(NG * NP), dim3(256), 0, stream>>>(
        gal, prob, bn_w, bn_b, bn_m, bn_v, fc_w, fc_b, lbn_w, lbn_b, lbn_m, lbn_v, out);
  }
}